// Round 11
// baseline (1392.850 us; speedup 1.0000x reference)
//
#include <hip/hip_runtime.h>
#include <cstdint>
#include <cstddef>

#define NN   2048
#define BB   16
#define TT   12
#define FUT  12
#define HH   64
#define GG   256     // 4*H
#define KP   224     // K=198 padded to 7*32
#define ELLW 32      // max nnz/row; deg ~Poisson(8)+diag, P(>31) ~ 1e-11
#define ASTR 232     // LDS A row stride in shorts (464 B, 16B-aligned)

typedef __attribute__((ext_vector_type(8))) short bf16x8;
typedef __attribute__((ext_vector_type(4))) float f32x4;

__device__ __forceinline__ float sigmoidf_(float x) {
    return 1.f / (1.f + __expf(-x));
}
__device__ __forceinline__ float tanhf_(float x) {
    const float e = __expf(2.f * x);
    return 1.f - 2.f / (e + 1.f);
}
__device__ __forceinline__ unsigned short f2bf(float x) {
    unsigned u = __builtin_bit_cast(unsigned, x);
    u += 0x7fffu + ((u >> 16) & 1u);
    return (unsigned short)(u >> 16);
}
__device__ __forceinline__ float bf2f(unsigned short s) {
    unsigned u = ((unsigned)s) << 16;
    return __builtin_bit_cast(float, u);
}

// state layout: s[p][n][bb][64], p=0..7 (XCD slab), b = 2p+bb
__device__ __forceinline__ size_t idxH(int p, int n, int bb) {
    return ((((size_t)p * NN + n) << 1) + bb) << 6;
}
__device__ __forceinline__ size_t idxX(int p, int n, int bb) {
    return ((((size_t)p * NN + n) << 1) + bb) << 1;
}

// ---------------------------------------------------------------------------
// ELL of L, deterministic ascending-column order, padded to FULL ELLW with
// (col=n, val=0) -> exact no-ops; cnt = real nnz count.
// ---------------------------------------------------------------------------
__global__ __launch_bounds__(256) void build_ell(
    const float* __restrict__ L, int* __restrict__ cols,
    float* __restrict__ vals, int* __restrict__ cnt)
{
    const int n = blockIdx.x;
    const int t = threadIdx.x;
    const float* row = L + (size_t)n * NN;
    float v[8];
    int c = 0;
#pragma unroll
    for (int i = 0; i < 8; ++i) {
        v[i] = row[t * 8 + i];
        c += (v[i] != 0.f);
    }
    __shared__ int s[256];
    s[t] = c;
    __syncthreads();
    for (int d = 1; d < 256; d <<= 1) {
        int add = (t >= d) ? s[t - d] : 0;
        __syncthreads();
        s[t] += add;
        __syncthreads();
    }
    int o = s[t] - c;
#pragma unroll
    for (int i = 0; i < 8; ++i) {
        if (v[i] != 0.f) {
            if (o < ELLW) {
                cols[n * ELLW + o] = t * 8 + i;
                vals[n * ELLW + o] = v[i];
            }
            ++o;
        }
    }
    const int cn = (s[255] < ELLW) ? s[255] : ELLW;
    for (int pp = cn + t; pp < ELLW; pp += 256) {
        cols[n * ELLW + pp] = n;
        vals[n * ELLW + pp] = 0.f;
    }
    if (t == 255) cnt[n] = cn;
}

// ---------------------------------------------------------------------------
// W [198][256] fp32 -> W_t hi/lo [256][224] bf16 (transposed, K-padded).
// ---------------------------------------------------------------------------
__global__ __launch_bounds__(256) void wt_prep(
    const float* __restrict__ W, short* __restrict__ Wh, short* __restrict__ Wl)
{
    const int col = blockIdx.x;
    const int k = threadIdx.x;
    if (k < KP) {
        const float x = (k < 198) ? W[(size_t)k * GG + col] : 0.f;
        const unsigned short h = f2bf(x);
        const unsigned short l = f2bf(x - bf2f(h));
        Wh[(size_t)col * KP + k] = (short)h;
        Wl[(size_t)col * KP + k] = (short)l;
    }
}

// ---------------------------------------------------------------------------
// input [B][T][N][2] -> xts [T][8][N][2][2]  (slab-major x)
// ---------------------------------------------------------------------------
__global__ __launch_bounds__(256) void x_trans(
    const float* __restrict__ input, float* __restrict__ xt)
{
    const int o = blockIdx.x * 256 + threadIdx.x;   // 786432 total
    const int e = o & 1;
    const int bb = (o >> 1) & 1;
    const int n = (o >> 2) & (NN - 1);
    const int p = (o >> 13) & 7;
    const int t = o >> 16;
    const int b = p * 2 + bb;
    xt[o] = input[(((size_t)b * TT + t) * NN + n) * 2 + e];
}

// ---------------------------------------------------------------------------
// t1 = L @ comb (slab p).  Grid 2048: p = bid&7 (XCD-local slab), 8 nodes/blk.
// Thread: row = t>>4 (node_sub*2+bb), q = t&15 -> floats [4q,4q+4).
// q==0 also accumulates the 2-wide x-part.
// ---------------------------------------------------------------------------
__global__ __launch_bounds__(256, 8) void spmm_t1(
    const float* __restrict__ xt,      // [8][N][2][2] (this step's slice)
    const float* __restrict__ hs,      // [8][N][2][64]
    const int* __restrict__ cols, const float* __restrict__ vals,
    const int* __restrict__ cnt,
    float* __restrict__ t1s, float* __restrict__ t1xs)
{
    const int bid = blockIdx.x;
    const int p = bid & 7, g = bid >> 3;
    const int t = threadIdx.x;
    const int row = t >> 4, q = t & 15;
    const int n = g * 8 + (row >> 1), bb = row & 1;
    const int cn4 = (cnt[n] + 3) & ~3;
    const int* cp = cols + n * ELLW;
    const float* vp = vals + n * ELLW;
    const size_t slabH = (size_t)p * NN * 2 * 64;
    float a0 = 0.f, a1 = 0.f, a2 = 0.f, a3 = 0.f;
    float ax0 = 0.f, ax1 = 0.f;
#pragma unroll 2
    for (int jj = 0; jj < cn4; jj += 4) {
#pragma unroll
        for (int u = 0; u < 4; ++u) {
            const int m = cp[jj + u];
            const float v = vp[jj + u];
            const float4 gq = *(const float4*)&hs[idxH(p, m, bb) + 4 * q];
            a0 += v * gq.x; a1 += v * gq.y; a2 += v * gq.z; a3 += v * gq.w;
            if (q == 0) {
                const float2 xg = *(const float2*)&xt[idxX(p, m, bb)];
                ax0 += v * xg.x; ax1 += v * xg.y;
            }
        }
    }
    *(float4*)&t1s[idxH(p, n, bb) + 4 * q] = (float4){a0, a1, a2, a3};
    if (q == 0) {
        t1xs[idxX(p, n, bb)]     = ax0;
        t1xs[idxX(p, n, bb) + 1] = ax1;
    }
}

// ---------------------------------------------------------------------------
// Fused cell step, slab-major: grid 1024, p = bid&7 (XCD-local), 16 nodes/blk,
// 32 A-rows (row = node_sub*2 + bb), 4 blocks/CU.
//   phase 1: 2 tasks/thread (rows t>>4 and +16, quad q=t&15): stage h/t1,
//            gather t2 from L2-resident t1 slab, bf16 hi/lo split -> LDS.
//   phase 2: MFMA GEMM; wave w owns gate-strided col-tiles {w,w+4,w+8,w+12}.
//   phase 3: LSTM elementwise; projection via LDS reduce.
// A k-cols: [0..65]=comb(x0,x1,h0..63)  [66..131]=t1  [132..197]=t2  [198..]=0
// ---------------------------------------------------------------------------
__global__ __launch_bounds__(256, 4) void cell_fused(
    const float* __restrict__ xt,      // [8][N][2][2] (this step's slice)
    float* __restrict__ hs, float* __restrict__ cs,   // [8][N][2][64]
    const float* __restrict__ t1s,     // [8][N][2][64]
    const float* __restrict__ t1xs,    // [8][N][2][2]
    const int* __restrict__ cols, const float* __restrict__ vals,
    const int* __restrict__ cnt,
    const short* __restrict__ Wh, const short* __restrict__ Wl,
    const float* __restrict__ bc,
    const float* __restrict__ W0, const float* __restrict__ b0,
    float* __restrict__ xouts,         // [8][N][2][2]
    float* __restrict__ out, int jslot)
{
    __shared__ unsigned short Ah[32][ASTR];
    __shared__ unsigned short Al[32][ASTR];
    __shared__ float proj[4][32][2];
    const int tid = threadIdx.x, w = tid >> 6, lane = tid & 63;
    const int qw = lane >> 4, c16 = lane & 15;
    const int bid = blockIdx.x;
    const int p = bid & 7, g = bid >> 3;
    const int n0 = g * 16;

    auto put = [&](int r, int k, float v) {
        const unsigned short hi = f2bf(v);
        Ah[r][k] = hi;
        Al[r][k] = f2bf(v - bf2f(hi));
    };

    // ---- zero pad cols 198..231
    {
        const int zr = tid >> 3, zs = tid & 7;
#pragma unroll
        for (int k0 = 198; k0 < 232; k0 += 8) {
            const int k = k0 + zs;
            if (k < 232) { Ah[zr][k] = 0; Al[zr][k] = 0; }
        }
    }

    // ---- phase 1: stage + t2 gather (2 tasks per thread)
#pragma unroll
    for (int half = 0; half < 2; ++half) {
        const int r = (tid >> 4) + half * 16;       // A-row 0..31
        const int q = tid & 15;
        const int n = n0 + (r >> 1), bb = r & 1;
        const size_t rbase = idxH(p, n, bb);
        const float4 hq = *(const float4*)&hs[rbase + 4 * q];
        const float4 tq = *(const float4*)&t1s[rbase + 4 * q];
        float xo0 = 0.f, xo1 = 0.f, t160 = 0.f, t161 = 0.f;
        if (q == 0) {
            const float2 xv = *(const float2*)&xt[idxX(p, n, bb)];
            xo0 = xv.x; xo1 = xv.y;
            const float2 tv = *(const float2*)&t1xs[idxX(p, n, bb)];
            t160 = tv.x; t161 = tv.y;
        }
        const int cn4 = (cnt[n] + 3) & ~3;
        const int* cp = cols + n * ELLW;
        const float* vp = vals + n * ELLW;
        float a0 = 0.f, a1 = 0.f, a2 = 0.f, a3 = 0.f, ax0 = 0.f, ax1 = 0.f;
#pragma unroll 2
        for (int jj = 0; jj < cn4; jj += 4) {
#pragma unroll
            for (int u = 0; u < 4; ++u) {
                const int m = cp[jj + u];
                const float v = vp[jj + u];
                const float4 gq = *(const float4*)&t1s[idxH(p, m, bb) + 4 * q];
                a0 += v * gq.x; a1 += v * gq.y; a2 += v * gq.z; a3 += v * gq.w;
                if (q == 0) {
                    const float2 gx = *(const float2*)&t1xs[idxX(p, m, bb)];
                    ax0 += v * gx.x; ax1 += v * gx.y;
                }
            }
        }
        const int ko = 4 * q;
        put(r, 2 + ko + 0, hq.x);  put(r, 2 + ko + 1, hq.y);
        put(r, 2 + ko + 2, hq.z);  put(r, 2 + ko + 3, hq.w);
        put(r, 68 + ko + 0, tq.x); put(r, 68 + ko + 1, tq.y);
        put(r, 68 + ko + 2, tq.z); put(r, 68 + ko + 3, tq.w);
        put(r, 134 + ko + 0, 2.f * a0 - hq.x);
        put(r, 134 + ko + 1, 2.f * a1 - hq.y);
        put(r, 134 + ko + 2, 2.f * a2 - hq.z);
        put(r, 134 + ko + 3, 2.f * a3 - hq.w);
        if (q == 0) {
            put(r, 0, xo0);   put(r, 1, xo1);
            put(r, 66, t160); put(r, 67, t161);
            put(r, 132, 2.f * ax0 - xo0);
            put(r, 133, 2.f * ax1 - xo1);
        }
    }
    __syncthreads();

    // ---- phase 2: MFMA GEMM (2 row-tiles x 4 gate-tiles)
    f32x4 acc[2][4];
#pragma unroll
    for (int rt = 0; rt < 2; ++rt)
#pragma unroll
        for (int gg2 = 0; gg2 < 4; ++gg2) acc[rt][gg2] = (f32x4){0.f, 0.f, 0.f, 0.f};

    for (int kc = 0; kc < 7; ++kc) {
        const int ko = kc * 32 + qw * 8;
        bf16x8 ah[2], al[2];
#pragma unroll
        for (int rt = 0; rt < 2; ++rt) {
            ah[rt] = *(const bf16x8*)&Ah[rt * 16 + c16][ko];
            al[rt] = *(const bf16x8*)&Al[rt * 16 + c16][ko];
        }
        bf16x8 bh[4], bl[4];
#pragma unroll
        for (int gg2 = 0; gg2 < 4; ++gg2) {
            const int col = (w + 4 * gg2) * 16 + c16;
            const size_t wo = (size_t)col * KP + ko;
            bh[gg2] = *(const bf16x8*)(Wh + wo);
            bl[gg2] = *(const bf16x8*)(Wl + wo);
        }
#pragma unroll
        for (int rt = 0; rt < 2; ++rt)
#pragma unroll
            for (int gg2 = 0; gg2 < 4; ++gg2) {
                acc[rt][gg2] = __builtin_amdgcn_mfma_f32_16x16x32_bf16(ah[rt], bh[gg2], acc[rt][gg2], 0, 0, 0);
                acc[rt][gg2] = __builtin_amdgcn_mfma_f32_16x16x32_bf16(al[rt], bh[gg2], acc[rt][gg2], 0, 0, 0);
                acc[rt][gg2] = __builtin_amdgcn_mfma_f32_16x16x32_bf16(ah[rt], bl[gg2], acc[rt][gg2], 0, 0, 0);
            }
    }

    // ---- phase 3: LSTM elementwise (unit u = 16*w + c16 lane-local)
    const int u = 16 * w + c16;
    const float bi = bc[u], bfv = bc[64 + u], bo = bc[128 + u], bg = bc[192 + u];
    const size_t blk = ((size_t)p * NN + n0) * 2 * 64;   // block's state base
    float h2v[2][4];
#pragma unroll
    for (int rt = 0; rt < 2; ++rt) {
#pragma unroll
        for (int reg = 0; reg < 4; ++reg) {
            const int row = rt * 16 + qw * 4 + reg;      // A-row 0..31
            const size_t idx = blk + (size_t)row * 64 + u;
            const float ig = sigmoidf_(acc[rt][0][reg] + bi);
            const float fg = sigmoidf_(acc[rt][1][reg] + bfv);
            const float og = sigmoidf_(acc[rt][2][reg] + bo);
            const float gg2 = tanhf_(acc[rt][3][reg] + bg);
            const float c2 = fg * cs[idx] + ig * gg2;
            const float h2 = og * tanhf_(c2);
            cs[idx] = c2;
            hs[idx] = h2;
            h2v[rt][reg] = h2;
        }
    }

    if (jslot >= 0) {
        const float w0u = W0[u * 2], w1u = W0[u * 2 + 1];
#pragma unroll
        for (int rt = 0; rt < 2; ++rt) {
#pragma unroll
            for (int reg = 0; reg < 4; ++reg) {
                float s0 = h2v[rt][reg] * w0u;
                float s1 = h2v[rt][reg] * w1u;
#pragma unroll
                for (int d = 1; d <= 8; d <<= 1) {
                    s0 += __shfl_xor(s0, d, 64);
                    s1 += __shfl_xor(s1, d, 64);
                }
                if (c16 == 0) {
                    const int lr = rt * 16 + qw * 4 + reg;
                    proj[w][lr][0] = s0;
                    proj[w][lr][1] = s1;
                }
            }
        }
        __syncthreads();
        if (tid < 64) {
            const int lr = tid >> 1, comp = tid & 1;
            const float v = proj[0][lr][comp] + proj[1][lr][comp] +
                            proj[2][lr][comp] + proj[3][lr][comp] + b0[comp];
            const float y = tanhf_(v);
            const int n = n0 + (lr >> 1), bb = lr & 1;
            const int b = p * 2 + bb;
            xouts[idxX(p, n, bb) + comp] = y;
            out[(((size_t)b * FUT + jslot) * NN + n) * 2 + comp] = y;
        }
    }
}

// ---------------------------------------------------------------------------
extern "C" void kernel_launch(void* const* d_in, const int* in_sizes, int n_in,
                              void* d_out, int out_size, void* d_ws, size_t ws_size,
                              hipStream_t stream)
{
    const float* input = (const float*)d_in[0];   // [B,T,N,2]
    const float* L     = (const float*)d_in[1];   // [N,N]
    const float* W     = (const float*)d_in[2];   // [198,256]
    const float* bc    = (const float*)d_in[3];   // [256]
    const float* W0    = (const float*)d_in[4];   // [64,2]
    const float* b0    = (const float*)d_in[5];   // [2]

    char* ws = (char*)d_ws;
    size_t off = 0;
    auto carve = [&](size_t bytes) {
        void* p = ws + off;
        off += (bytes + 255) & ~(size_t)255;
        return p;
    };
    int*   cols  = (int*)  carve((size_t)NN * ELLW * 4);
    float* vals  = (float*)carve((size_t)NN * ELLW * 4);
    int*   cnt   = (int*)  carve((size_t)NN * 4);
    float* t1s   = (float*)carve((size_t)NN * 16 * HH * 4);
    float* t1xs  = (float*)carve((size_t)NN * 16 * 2 * 4);
    float* hs    = (float*)carve((size_t)NN * 16 * HH * 4);
    float* cs    = (float*)carve((size_t)NN * 16 * HH * 4);
    float* xbuf  = (float*)carve((size_t)NN * 16 * 2 * 4);
    float* xtall = (float*)carve((size_t)TT * NN * 16 * 2 * 4);
    short* Wh    = (short*)carve((size_t)GG * KP * 2);
    short* Wl    = (short*)carve((size_t)GG * KP * 2);
    float* out   = (float*)d_out;

    build_ell<<<NN, 256, 0, stream>>>(L, cols, vals, cnt);
    wt_prep<<<GG, 256, 0, stream>>>(W, Wh, Wl);
    x_trans<<<(TT * NN * 16 * 2) / 256, 256, 0, stream>>>(input, xtall);
    hipMemsetAsync(hs, 0, (size_t)NN * 16 * HH * 4, stream);
    hipMemsetAsync(cs, 0, (size_t)NN * 16 * HH * 4, stream);

    for (int t = 0; t < TT; ++t) {
        const float* xt = xtall + (size_t)t * NN * 16 * 2;
        spmm_t1<<<NN, 256, 0, stream>>>(xt, hs, cols, vals, cnt, t1s, t1xs);
        cell_fused<<<NN / 2, 256, 0, stream>>>(xt, hs, cs, t1s, t1xs, cols, vals, cnt,
                                               Wh, Wl, bc, W0, b0, xbuf, out,
                                               (t == TT - 1) ? 0 : -1);
    }
    for (int jstep = 1; jstep < FUT; ++jstep) {
        spmm_t1<<<NN, 256, 0, stream>>>(xbuf, hs, cols, vals, cnt, t1s, t1xs);
        cell_fused<<<NN / 2, 256, 0, stream>>>(xbuf, hs, cs, t1s, t1xs, cols, vals, cnt,
                                               Wh, Wl, bc, W0, b0, xbuf, out, jstep);
    }
}

// Round 12
// 1294.454 us; speedup vs baseline: 1.0760x; 1.0760x over previous
//
#include <hip/hip_runtime.h>
#include <cstdint>
#include <cstddef>

#define NN   2048
#define BB   16
#define TT   12
#define FUT  12
#define HH   64
#define GG   256     // 4*H
#define KP   224     // K=198 padded to 7*32
#define ELLW 32      // max nnz/row (verified: r11 passed bitwise-identical)
#define ASTR 232     // LDS A row stride in shorts (464 B, 16B-aligned)

typedef __attribute__((ext_vector_type(8))) short bf16x8;
typedef __attribute__((ext_vector_type(4))) float f32x4;

__device__ __forceinline__ float sigmoidf_(float x) {
    return 1.f / (1.f + __expf(-x));
}
__device__ __forceinline__ float tanhf_(float x) {
    const float e = __expf(2.f * x);
    return 1.f - 2.f / (e + 1.f);
}
__device__ __forceinline__ unsigned short f2bf(float x) {
    unsigned u = __builtin_bit_cast(unsigned, x);
    u += 0x7fffu + ((u >> 16) & 1u);
    return (unsigned short)(u >> 16);
}
__device__ __forceinline__ float bf2f(unsigned short s) {
    unsigned u = ((unsigned)s) << 16;
    return __builtin_bit_cast(float, u);
}

// ---------------------------------------------------------------------------
// ELL of L, deterministic ascending-column order, padded to FULL ELLW with
// (col=n, val=0) -> exact no-ops; cnt = real nnz count.
// ---------------------------------------------------------------------------
__global__ __launch_bounds__(256) void build_ell(
    const float* __restrict__ L, int* __restrict__ cols,
    float* __restrict__ vals, int* __restrict__ cnt)
{
    const int n = blockIdx.x;
    const int t = threadIdx.x;
    const float* row = L + (size_t)n * NN;
    float v[8];
    int c = 0;
#pragma unroll
    for (int i = 0; i < 8; ++i) {
        v[i] = row[t * 8 + i];
        c += (v[i] != 0.f);
    }
    __shared__ int s[256];
    s[t] = c;
    __syncthreads();
    for (int d = 1; d < 256; d <<= 1) {
        int add = (t >= d) ? s[t - d] : 0;
        __syncthreads();
        s[t] += add;
        __syncthreads();
    }
    int o = s[t] - c;
#pragma unroll
    for (int i = 0; i < 8; ++i) {
        if (v[i] != 0.f) {
            if (o < ELLW) {
                cols[n * ELLW + o] = t * 8 + i;
                vals[n * ELLW + o] = v[i];
            }
            ++o;
        }
    }
    const int cn = (s[255] < ELLW) ? s[255] : ELLW;
    for (int p = cn + t; p < ELLW; p += 256) {
        cols[n * ELLW + p] = n;
        vals[n * ELLW + p] = 0.f;
    }
    if (t == 255) cnt[n] = cn;
}

// ---------------------------------------------------------------------------
// W [198][256] fp32 -> W_t hi/lo [256][224] bf16 (transposed, K-padded).
// ---------------------------------------------------------------------------
__global__ __launch_bounds__(256) void wt_prep(
    const float* __restrict__ W, short* __restrict__ Wh, short* __restrict__ Wl)
{
    const int col = blockIdx.x;
    const int k = threadIdx.x;
    if (k < KP) {
        const float x = (k < 198) ? W[(size_t)k * GG + col] : 0.f;
        const unsigned short h = f2bf(x);
        const unsigned short l = f2bf(x - bf2f(h));
        Wh[(size_t)col * KP + k] = (short)h;
        Wl[(size_t)col * KP + k] = (short)l;
    }
}

// ---------------------------------------------------------------------------
// input [B][T][N][2] -> xt_all [T][N][B][2]  (node-major x, batch inner)
// ---------------------------------------------------------------------------
__global__ __launch_bounds__(256) void x_trans(
    const float* __restrict__ input, float* __restrict__ xt)
{
    const int o = blockIdx.x * 256 + threadIdx.x;   // 786432 total
    const int e = o & 1;
    const int b = (o >> 1) & 15;
    const int n = (o >> 5) & (NN - 1);
    const int t = o >> 16;
    xt[o] = input[(((size_t)b * TT + t) * NN + n) * 2 + e];
}

// ---------------------------------------------------------------------------
// t1h[n][b][0..63] / t1x[n][b][0..1] = L_row(n) @ comb.
// One block per node (2048 blocks, 8/CU), 4 waves = 4 h-quad-slices,
// lane = (b=lane>>2, j=lane&3).
// ---------------------------------------------------------------------------
__global__ __launch_bounds__(256, 8) void spmm_t1(
    const float* __restrict__ xt,      // [N][16][2]
    const float* __restrict__ h,       // [N][16][64]
    const int* __restrict__ cols, const float* __restrict__ vals,
    const int* __restrict__ cnt,
    float* __restrict__ t1h, float* __restrict__ t1x)
{
    const int w = threadIdx.x >> 6, lane = threadIdx.x & 63;
    const int b = lane >> 2, j = lane & 3;
    const int n = blockIdx.x;
    const int cn4 = (cnt[n] + 3) & ~3;
    const int* cp = cols + n * ELLW;
    const float* vp = vals + n * ELLW;
    const int qoff = (4 * w + j) * 4;
    float a0 = 0.f, a1 = 0.f, a2 = 0.f, a3 = 0.f;
    float ax0 = 0.f, ax1 = 0.f;
#pragma unroll 2
    for (int jj = 0; jj < cn4; jj += 4) {
#pragma unroll
        for (int u = 0; u < 4; ++u) {
            const int m = cp[jj + u];
            const float v = vp[jj + u];
            const size_t mb = (size_t)m * 16 + b;
            const float4 g = *(const float4*)&h[mb * HH + qoff];
            a0 += v * g.x; a1 += v * g.y; a2 += v * g.z; a3 += v * g.w;
            if (w == 0) {
                const float2 xg = *(const float2*)&xt[mb * 2];
                ax0 += v * xg.x; ax1 += v * xg.y;
            }
        }
    }
    *(float4*)&t1h[((size_t)n * 16 + b) * HH + qoff] = (float4){a0, a1, a2, a3};
    if (w == 0 && j == 0) {
        t1x[((size_t)n * 16 + b) * 2]     = ax0;
        t1x[((size_t)n * 16 + b) * 2 + 1] = ax1;
    }
}

// ---------------------------------------------------------------------------
// t2h/t2x = 2 * (L @ t1) - comb.  Same structure/occupancy as spmm_t1.
// ---------------------------------------------------------------------------
__global__ __launch_bounds__(256, 8) void spmm_t2(
    const float* __restrict__ xt,      // [N][16][2]
    const float* __restrict__ h,       // [N][16][64]
    const float* __restrict__ t1h,     // [N][16][64]
    const float* __restrict__ t1x,     // [N][16][2]
    const int* __restrict__ cols, const float* __restrict__ vals,
    const int* __restrict__ cnt,
    float* __restrict__ t2h, float* __restrict__ t2x)
{
    const int w = threadIdx.x >> 6, lane = threadIdx.x & 63;
    const int b = lane >> 2, j = lane & 3;
    const int n = blockIdx.x;
    const int cn4 = (cnt[n] + 3) & ~3;
    const int* cp = cols + n * ELLW;
    const float* vp = vals + n * ELLW;
    const int qoff = (4 * w + j) * 4;
    float a0 = 0.f, a1 = 0.f, a2 = 0.f, a3 = 0.f;
    float ax0 = 0.f, ax1 = 0.f;
#pragma unroll 2
    for (int jj = 0; jj < cn4; jj += 4) {
#pragma unroll
        for (int u = 0; u < 4; ++u) {
            const int m = cp[jj + u];
            const float v = vp[jj + u];
            const size_t mb = (size_t)m * 16 + b;
            const float4 g = *(const float4*)&t1h[mb * HH + qoff];
            a0 += v * g.x; a1 += v * g.y; a2 += v * g.z; a3 += v * g.w;
            if (w == 0) {
                const float2 gx = *(const float2*)&t1x[mb * 2];
                ax0 += v * gx.x; ax1 += v * gx.y;
            }
        }
    }
    const size_t rb = (size_t)n * 16 + b;
    const float4 hq = *(const float4*)&h[rb * HH + qoff];
    *(float4*)&t2h[rb * HH + qoff] =
        (float4){2.f * a0 - hq.x, 2.f * a1 - hq.y, 2.f * a2 - hq.z, 2.f * a3 - hq.w};
    if (w == 0 && j == 0) {
        const float2 xv = *(const float2*)&xt[rb * 2];
        t2x[rb * 2]     = 2.f * ax0 - xv.x;
        t2x[rb * 2 + 1] = 2.f * ax1 - xv.y;
    }
}

// ---------------------------------------------------------------------------
// Gather-free fused cell step: block = 4 nodes x 16 batches = 64 A-rows,
// grid 512 -> 2 blocks/CU.  Halves per-CU W L2-streaming vs 32-row blocks.
//   phase 1: coalesced float4 reads of h/t1h/t2h rows, bf16 hi/lo split, LDS.
//   phase 2: MFMA GEMM; wave w owns gate-strided col-tiles {w,w+4,w+8,w+12},
//            4 row-tiles; 48 MFMA per 8 B-loads per kc.
//   phase 3: LSTM elementwise; projection via LDS reduce.
// A k-cols: [0..65]=comb(x0,x1,h0..63)  [66..131]=t1  [132..197]=t2  [198..]=0
// ---------------------------------------------------------------------------
__global__ __launch_bounds__(256, 2) void cell_fused(
    const float* __restrict__ xt,      // [N][16][2]
    float* __restrict__ h, float* __restrict__ c,   // [N][16][64]
    const float* __restrict__ t1h, const float* __restrict__ t1x,
    const float* __restrict__ t2h, const float* __restrict__ t2x,
    const short* __restrict__ Wh, const short* __restrict__ Wl,
    const float* __restrict__ bc,
    const float* __restrict__ W0, const float* __restrict__ b0,
    float* __restrict__ xout,          // [N][16][2]
    float* __restrict__ out, int jslot)
{
    __shared__ unsigned short Ah[64][ASTR];
    __shared__ unsigned short Al[64][ASTR];
    __shared__ float proj[4][64][2];
    const int tid = threadIdx.x, w = tid >> 6, lane = tid & 63;
    const int q = lane >> 4, c16 = lane & 15;
    const int b = lane >> 2, j = lane & 3;
    const int n0 = blockIdx.x * 4;
    const int qoff = (4 * w + j) * 4;            // f-slice float offset (0..60)

    auto put = [&](int r, int k, float v) {
        const unsigned short hi = f2bf(v);
        Ah[r][k] = hi;
        Al[r][k] = f2bf(v - bf2f(hi));
    };

    // ---- zero pad cols 198..231 (64 rows x 34 cols)
    {
        const int zr = tid >> 2, zs = tid & 3;
        for (int k = 198 + zs; k < 232; k += 4) {
            Ah[zr][k] = 0; Al[zr][k] = 0;
        }
    }

    // ---- phase 1: coalesced stage (no gather)
#pragma unroll
    for (int ln = 0; ln < 4; ++ln) {
        const int n = n0 + ln;
        const size_t rb = (size_t)n * 16 + b;
        const int r = ln * 16 + b;
        const float4 hq = *(const float4*)&h[rb * HH + qoff];
        const float4 tq = *(const float4*)&t1h[rb * HH + qoff];
        const float4 zq = *(const float4*)&t2h[rb * HH + qoff];
        put(r, 2 + qoff + 0, hq.x);   put(r, 2 + qoff + 1, hq.y);
        put(r, 2 + qoff + 2, hq.z);   put(r, 2 + qoff + 3, hq.w);
        put(r, 68 + qoff + 0, tq.x);  put(r, 68 + qoff + 1, tq.y);
        put(r, 68 + qoff + 2, tq.z);  put(r, 68 + qoff + 3, tq.w);
        put(r, 134 + qoff + 0, zq.x); put(r, 134 + qoff + 1, zq.y);
        put(r, 134 + qoff + 2, zq.z); put(r, 134 + qoff + 3, zq.w);
        if (w == 1 && j == 0) {
            const float2 xv = *(const float2*)&xt[rb * 2];
            const float2 tv = *(const float2*)&t1x[rb * 2];
            const float2 zv = *(const float2*)&t2x[rb * 2];
            put(r, 0, xv.x);   put(r, 1, xv.y);
            put(r, 66, tv.x);  put(r, 67, tv.y);
            put(r, 132, zv.x); put(r, 133, zv.y);
        }
    }
    __syncthreads();

    // ---- phase 2: MFMA GEMM (4 row-tiles x 4 gate-tiles)
    f32x4 acc[4][4];
#pragma unroll
    for (int rt = 0; rt < 4; ++rt)
#pragma unroll
        for (int g = 0; g < 4; ++g) acc[rt][g] = (f32x4){0.f, 0.f, 0.f, 0.f};

    for (int kc = 0; kc < 7; ++kc) {
        const int ko = kc * 32 + q * 8;
        bf16x8 bh[4], bl[4];
#pragma unroll
        for (int g = 0; g < 4; ++g) {
            const int col = (w + 4 * g) * 16 + c16;
            const size_t wo = (size_t)col * KP + ko;
            bh[g] = *(const bf16x8*)(Wh + wo);
            bl[g] = *(const bf16x8*)(Wl + wo);
        }
        bf16x8 ah[4], al[4];
#pragma unroll
        for (int rt = 0; rt < 4; ++rt) {
            ah[rt] = *(const bf16x8*)&Ah[rt * 16 + c16][ko];
            al[rt] = *(const bf16x8*)&Al[rt * 16 + c16][ko];
        }
#pragma unroll
        for (int rt = 0; rt < 4; ++rt)
#pragma unroll
            for (int g = 0; g < 4; ++g) {
                acc[rt][g] = __builtin_amdgcn_mfma_f32_16x16x32_bf16(ah[rt], bh[g], acc[rt][g], 0, 0, 0);
                acc[rt][g] = __builtin_amdgcn_mfma_f32_16x16x32_bf16(al[rt], bh[g], acc[rt][g], 0, 0, 0);
                acc[rt][g] = __builtin_amdgcn_mfma_f32_16x16x32_bf16(ah[rt], bl[g], acc[rt][g], 0, 0, 0);
            }
    }

    // ---- phase 3: LSTM elementwise (unit u = 16*w + c16 lane-local)
    const int u = 16 * w + c16;
    const float bi = bc[u], bfv = bc[64 + u], bo = bc[128 + u], bg = bc[192 + u];
    float h2v[4][4];
#pragma unroll
    for (int rt = 0; rt < 4; ++rt) {
        const int n = n0 + rt;
#pragma unroll
        for (int reg = 0; reg < 4; ++reg) {
            const int bb = q * 4 + reg;
            const size_t idx = ((size_t)n * 16 + bb) * HH + u;
            const float ig = sigmoidf_(acc[rt][0][reg] + bi);
            const float fg = sigmoidf_(acc[rt][1][reg] + bfv);
            const float og = sigmoidf_(acc[rt][2][reg] + bo);
            const float gg = tanhf_(acc[rt][3][reg] + bg);
            const float c2 = fg * c[idx] + ig * gg;
            const float h2 = og * tanhf_(c2);
            c[idx] = c2;
            h[idx] = h2;
            h2v[rt][reg] = h2;
        }
    }

    if (jslot >= 0) {
        const float w0u = W0[u * 2], w1u = W0[u * 2 + 1];
#pragma unroll
        for (int rt = 0; rt < 4; ++rt) {
#pragma unroll
            for (int reg = 0; reg < 4; ++reg) {
                float s0 = h2v[rt][reg] * w0u;
                float s1 = h2v[rt][reg] * w1u;
#pragma unroll
                for (int d = 1; d <= 8; d <<= 1) {
                    s0 += __shfl_xor(s0, d, 64);
                    s1 += __shfl_xor(s1, d, 64);
                }
                if (c16 == 0) {
                    const int lr = rt * 16 + q * 4 + reg;
                    proj[w][lr][0] = s0;
                    proj[w][lr][1] = s1;
                }
            }
        }
        __syncthreads();
        if (tid < 128) {
            const int lr = tid >> 1, comp = tid & 1;
            const float v = proj[0][lr][comp] + proj[1][lr][comp] +
                            proj[2][lr][comp] + proj[3][lr][comp] + b0[comp];
            const float y = tanhf_(v);
            const int n = n0 + (lr >> 4);
            const int bb = lr & 15;
            xout[((size_t)n * 16 + bb) * 2 + comp] = y;
            out[(((size_t)bb * FUT + jslot) * NN + n) * 2 + comp] = y;
        }
    }
}

// ---------------------------------------------------------------------------
extern "C" void kernel_launch(void* const* d_in, const int* in_sizes, int n_in,
                              void* d_out, int out_size, void* d_ws, size_t ws_size,
                              hipStream_t stream)
{
    const float* input = (const float*)d_in[0];   // [B,T,N,2]
    const float* L     = (const float*)d_in[1];   // [N,N]
    const float* W     = (const float*)d_in[2];   // [198,256]
    const float* bc    = (const float*)d_in[3];   // [256]
    const float* W0    = (const float*)d_in[4];   // [64,2]
    const float* b0    = (const float*)d_in[5];   // [2]

    char* ws = (char*)d_ws;
    size_t off = 0;
    auto carve = [&](size_t bytes) {
        void* p = ws + off;
        off += (bytes + 255) & ~(size_t)255;
        return p;
    };
    int*   cols  = (int*)  carve((size_t)NN * ELLW * 4);
    float* vals  = (float*)carve((size_t)NN * ELLW * 4);
    int*   cnt   = (int*)  carve((size_t)NN * 4);
    float* t1h   = (float*)carve((size_t)NN * 16 * HH * 4);
    float* t1x   = (float*)carve((size_t)NN * 16 * 2 * 4);
    float* t2h   = (float*)carve((size_t)NN * 16 * HH * 4);
    float* t2x   = (float*)carve((size_t)NN * 16 * 2 * 4);
    float* h     = (float*)carve((size_t)NN * 16 * HH * 4);
    float* c     = (float*)carve((size_t)NN * 16 * HH * 4);
    float* xbuf  = (float*)carve((size_t)NN * 16 * 2 * 4);
    float* xtall = (float*)carve((size_t)TT * NN * 16 * 2 * 4);
    short* Wh    = (short*)carve((size_t)GG * KP * 2);
    short* Wl    = (short*)carve((size_t)GG * KP * 2);
    float* out   = (float*)d_out;

    build_ell<<<NN, 256, 0, stream>>>(L, cols, vals, cnt);
    wt_prep<<<GG, 256, 0, stream>>>(W, Wh, Wl);
    x_trans<<<(TT * NN * 16 * 2) / 256, 256, 0, stream>>>(input, xtall);
    hipMemsetAsync(h, 0, (size_t)NN * 16 * HH * 4, stream);
    hipMemsetAsync(c, 0, (size_t)NN * 16 * HH * 4, stream);

    for (int t = 0; t < TT; ++t) {
        const float* xt = xtall + (size_t)t * NN * 16 * 2;
        spmm_t1<<<NN, 256, 0, stream>>>(xt, h, cols, vals, cnt, t1h, t1x);
        spmm_t2<<<NN, 256, 0, stream>>>(xt, h, t1h, t1x, cols, vals, cnt, t2h, t2x);
        cell_fused<<<NN / 4, 256, 0, stream>>>(xt, h, c, t1h, t1x, t2h, t2x,
                                               Wh, Wl, bc, W0, b0, xbuf, out,
                                               (t == TT - 1) ? 0 : -1);
    }
    for (int jstep = 1; jstep < FUT; ++jstep) {
        spmm_t1<<<NN, 256, 0, stream>>>(xbuf, h, cols, vals, cnt, t1h, t1x);
        spmm_t2<<<NN, 256, 0, stream>>>(xbuf, h, t1h, t1x, cols, vals, cnt, t2h, t2x);
        cell_fused<<<NN / 4, 256, 0, stream>>>(xbuf, h, c, t1h, t1x, t2h, t2x,
                                               Wh, Wl, bc, W0, b0, xbuf, out, jstep);
    }
}

// Round 13
// 1196.652 us; speedup vs baseline: 1.1640x; 1.0817x over previous
//
#include <hip/hip_runtime.h>
#include <cstdint>
#include <cstddef>

#define NN   2048
#define BB   16
#define TT   12
#define FUT  12
#define HH   64
#define GG   256     // 4*H
#define KP   224     // K=198 padded to 7*32
#define ELLW 32      // max nnz/row (validated bitwise in r11/r12)
#define ASTR 232     // LDS A row stride in shorts (464 B, 16B-aligned)

typedef __attribute__((ext_vector_type(8))) short bf16x8;
typedef __attribute__((ext_vector_type(4))) float f32x4;

__device__ __forceinline__ float sigmoidf_(float x) {
    return 1.f / (1.f + __expf(-x));
}
__device__ __forceinline__ float tanhf_(float x) {
    const float e = __expf(2.f * x);
    return 1.f - 2.f / (e + 1.f);
}
__device__ __forceinline__ unsigned short f2bf(float x) {
    unsigned u = __builtin_bit_cast(unsigned, x);
    u += 0x7fffu + ((u >> 16) & 1u);
    return (unsigned short)(u >> 16);
}
__device__ __forceinline__ float bf2f(unsigned short s) {
    unsigned u = ((unsigned)s) << 16;
    return __builtin_bit_cast(float, u);
}

// ---------------------------------------------------------------------------
// ELL of L, deterministic ascending-column order, padded to FULL ELLW with
// (col=n, val=0) -> exact no-ops; cnt = real nnz count.
// ---------------------------------------------------------------------------
__global__ __launch_bounds__(256) void build_ell(
    const float* __restrict__ L, int* __restrict__ cols,
    float* __restrict__ vals, int* __restrict__ cnt)
{
    const int n = blockIdx.x;
    const int t = threadIdx.x;
    const float* row = L + (size_t)n * NN;
    float v[8];
    int c = 0;
#pragma unroll
    for (int i = 0; i < 8; ++i) {
        v[i] = row[t * 8 + i];
        c += (v[i] != 0.f);
    }
    __shared__ int s[256];
    s[t] = c;
    __syncthreads();
    for (int d = 1; d < 256; d <<= 1) {
        int add = (t >= d) ? s[t - d] : 0;
        __syncthreads();
        s[t] += add;
        __syncthreads();
    }
    int o = s[t] - c;
#pragma unroll
    for (int i = 0; i < 8; ++i) {
        if (v[i] != 0.f) {
            if (o < ELLW) {
                cols[n * ELLW + o] = t * 8 + i;
                vals[n * ELLW + o] = v[i];
            }
            ++o;
        }
    }
    const int cn = (s[255] < ELLW) ? s[255] : ELLW;
    for (int p = cn + t; p < ELLW; p += 256) {
        cols[n * ELLW + p] = n;
        vals[n * ELLW + p] = 0.f;
    }
    if (t == 255) cnt[n] = cn;
}

// ---------------------------------------------------------------------------
// W [198][256] fp32 -> W_t hi/lo [256][224] bf16 (transposed, K-padded).
// ---------------------------------------------------------------------------
__global__ __launch_bounds__(256) void wt_prep(
    const float* __restrict__ W, short* __restrict__ Wh, short* __restrict__ Wl)
{
    const int col = blockIdx.x;
    const int k = threadIdx.x;
    if (k < KP) {
        const float x = (k < 198) ? W[(size_t)k * GG + col] : 0.f;
        const unsigned short h = f2bf(x);
        const unsigned short l = f2bf(x - bf2f(h));
        Wh[(size_t)col * KP + k] = (short)h;
        Wl[(size_t)col * KP + k] = (short)l;
    }
}

// ---------------------------------------------------------------------------
// input [B][T][N][2] -> xt_all [T][N][B][2]  (node-major x, batch inner)
// ---------------------------------------------------------------------------
__global__ __launch_bounds__(256) void x_trans(
    const float* __restrict__ input, float* __restrict__ xt)
{
    const int o = blockIdx.x * 256 + threadIdx.x;   // 786432 total
    const int e = o & 1;
    const int b = (o >> 1) & 15;
    const int n = (o >> 5) & (NN - 1);
    const int t = o >> 16;
    xt[o] = input[(((size_t)b * TT + t) * NN + n) * 2 + e];
}

// ---------------------------------------------------------------------------
// t1h[n][b][0..63] (h-part, 256B rows) and t1x[n][b][0..1] (x-part, dense).
// One block per node (2048 blocks, 8/CU), 4 waves = 4 h-quad-slices,
// lane = (b=lane>>2, j=lane&3).  int4/float4 meta chunk preloads.
// ---------------------------------------------------------------------------
__global__ __launch_bounds__(256, 8) void spmm_t1(
    const float* __restrict__ xt,      // [N][16][2]
    const float* __restrict__ h,       // [N][16][64]
    const int* __restrict__ cols, const float* __restrict__ vals,
    const int* __restrict__ cnt,
    float* __restrict__ t1h, float* __restrict__ t1x)
{
    const int w = threadIdx.x >> 6, lane = threadIdx.x & 63;
    const int b = lane >> 2, j = lane & 3;
    const int n = blockIdx.x;
    const int cn4 = (cnt[n] + 3) & ~3;
    const int* cp = cols + n * ELLW;
    const float* vp = vals + n * ELLW;
    const int qoff = (4 * w + j) * 4;
    float a0 = 0.f, a1 = 0.f, a2 = 0.f, a3 = 0.f;
    float ax0 = 0.f, ax1 = 0.f;

    auto acc1 = [&](int m, float v) {
        const size_t mb = (size_t)m * 16 + b;
        const float4 g = *(const float4*)&h[mb * HH + qoff];
        a0 += v * g.x; a1 += v * g.y; a2 += v * g.z; a3 += v * g.w;
        if (w == 0) {
            const float2 xg = *(const float2*)&xt[mb * 2];
            ax0 += v * xg.x; ax1 += v * xg.y;
        }
    };

#pragma unroll 2
    for (int jj = 0; jj < cn4; jj += 4) {
        const int4 cm = *(const int4*)(cp + jj);
        const float4 vm = *(const float4*)(vp + jj);
        acc1(cm.x, vm.x); acc1(cm.y, vm.y); acc1(cm.z, vm.z); acc1(cm.w, vm.w);
    }

    *(float4*)&t1h[((size_t)n * 16 + b) * HH + qoff] = (float4){a0, a1, a2, a3};
    if (w == 0 && j == 0) {
        t1x[((size_t)n * 16 + b) * 2]     = ax0;
        t1x[((size_t)n * 16 + b) * 2 + 1] = ax1;
    }
}

// ---------------------------------------------------------------------------
// Fused cell step (r8 structure): block = 2 nodes x 16 batches = 32 A-rows,
// grid 1024 -> 4 blocks/CU (30.7 KB LDS, VGPR capped 128 by (256,4)).
//   phase 1: stage comb/t1, gather t2 (int4 meta, coalesced 256B rows),
//            bf16 hi/lo split -> packed b32 LDS writes.
//   phase 2: MFMA GEMM; wave w owns gate-strided col-tiles {w,w+4,w+8,w+12};
//            kc-loop unroll-2 so W loads of kc+1 overlap kc's MFMAs.
//   phase 3: LSTM elementwise; projection via LDS reduce.
// A k-cols: [0..65]=comb(x0,x1,h0..63)  [66..131]=t1  [132..197]=t2  [198..]=0
// ---------------------------------------------------------------------------
__global__ __launch_bounds__(256, 4) void cell_fused(
    const float* __restrict__ xt,      // [N][16][2]
    float* __restrict__ h, float* __restrict__ c,   // [N][16][64]
    const float* __restrict__ t1h,     // [N][16][64]
    const float* __restrict__ t1x,     // [N][16][2]
    const int* __restrict__ cols, const float* __restrict__ vals,
    const int* __restrict__ cnt,
    const short* __restrict__ Wh, const short* __restrict__ Wl,
    const float* __restrict__ bc,
    const float* __restrict__ W0, const float* __restrict__ b0,
    float* __restrict__ xout,          // [N][16][2]
    float* __restrict__ out, int jslot)
{
    __shared__ unsigned short Ah[32][ASTR];
    __shared__ unsigned short Al[32][ASTR];
    __shared__ float proj[4][32][2];
    const int tid = threadIdx.x, w = tid >> 6, lane = tid & 63;
    const int q = lane >> 4, c16 = lane & 15;
    const int b = lane >> 2, j = lane & 3;
    const int n0 = blockIdx.x * 2;
    const int qoff = (4 * w + j) * 4;            // f-slice float offset (0..60)

    // pair-packed hi/lo LDS write: k must be even (all call sites are)
    auto put2 = [&](int r, int k, float v0, float v1) {
        const unsigned short h0 = f2bf(v0), h1 = f2bf(v1);
        const unsigned short l0 = f2bf(v0 - bf2f(h0));
        const unsigned short l1 = f2bf(v1 - bf2f(h1));
        *(unsigned*)(&Ah[r][k]) = (unsigned)h0 | ((unsigned)h1 << 16);
        *(unsigned*)(&Al[r][k]) = (unsigned)l0 | ((unsigned)l1 << 16);
    };

    // ---- zero pad cols 198..231
    {
        const int zr = tid >> 3, zs = tid & 7;
#pragma unroll
        for (int k0 = 198; k0 < 232; k0 += 8) {
            const int k = k0 + zs;
            if (k < 232) { Ah[zr][k] = 0; Al[zr][k] = 0; }
        }
    }

    // ---- phase 1: per node, stage + gather
#pragma unroll
    for (int ln = 0; ln < 2; ++ln) {
        const int n = n0 + ln;
        const size_t rb = (size_t)n * 16 + b;
        const int r = ln * 16 + b;
        const float4 hq = *(const float4*)&h[rb * HH + qoff];
        const float4 tq = *(const float4*)&t1h[rb * HH + qoff];
        float xo0 = 0.f, xo1 = 0.f, t160 = 0.f, t161 = 0.f;
        if (w == 1) {
            const float2 xv = *(const float2*)&xt[rb * 2];
            xo0 = xv.x; xo1 = xv.y;
            const float2 tv = *(const float2*)&t1x[rb * 2];
            t160 = tv.x; t161 = tv.y;
        }
        const int cn4 = (cnt[n] + 3) & ~3;
        const int* cp = cols + n * ELLW;
        const float* vp = vals + n * ELLW;
        float a0 = 0.f, a1 = 0.f, a2 = 0.f, a3 = 0.f, ax0 = 0.f, ax1 = 0.f;

        auto acc1 = [&](int m, float v) {
            const size_t mb = (size_t)m * 16 + b;
            const float4 g = *(const float4*)&t1h[mb * HH + qoff];
            a0 += v * g.x; a1 += v * g.y; a2 += v * g.z; a3 += v * g.w;
            if (w == 1) {
                const float2 gx = *(const float2*)&t1x[mb * 2];
                ax0 += v * gx.x; ax1 += v * gx.y;
            }
        };

#pragma unroll 2
        for (int jj = 0; jj < cn4; jj += 4) {
            const int4 cm = *(const int4*)(cp + jj);
            const float4 vm = *(const float4*)(vp + jj);
            acc1(cm.x, vm.x); acc1(cm.y, vm.y); acc1(cm.z, vm.z); acc1(cm.w, vm.w);
        }

        put2(r, 2 + qoff, hq.x, hq.y);
        put2(r, 4 + qoff, hq.z, hq.w);
        put2(r, 68 + qoff, tq.x, tq.y);
        put2(r, 70 + qoff, tq.z, tq.w);
        put2(r, 134 + qoff, 2.f * a0 - hq.x, 2.f * a1 - hq.y);
        put2(r, 136 + qoff, 2.f * a2 - hq.z, 2.f * a3 - hq.w);
        if (w == 1 && j == 0) {
            put2(r, 0, xo0, xo1);
            put2(r, 66, t160, t161);
            put2(r, 132, 2.f * ax0 - xo0, 2.f * ax1 - xo1);
        }
    }
    __syncthreads();

    // ---- phase 2: MFMA GEMM (2 row-tiles x 4 gate-tiles)
    f32x4 acc[2][4];
#pragma unroll
    for (int rt = 0; rt < 2; ++rt)
#pragma unroll
        for (int g = 0; g < 4; ++g) acc[rt][g] = (f32x4){0.f, 0.f, 0.f, 0.f};

    size_t colBase[4];
#pragma unroll
    for (int g = 0; g < 4; ++g)
        colBase[g] = (size_t)((w + 4 * g) * 16 + c16) * KP + q * 8;

#pragma unroll 2
    for (int kc = 0; kc < 7; ++kc) {
        const int ko = kc * 32;
        bf16x8 bh[4], bl[4];
#pragma unroll
        for (int g = 0; g < 4; ++g) {
            bh[g] = *(const bf16x8*)(Wh + colBase[g] + ko);
            bl[g] = *(const bf16x8*)(Wl + colBase[g] + ko);
        }
        bf16x8 ah[2], al[2];
#pragma unroll
        for (int rt = 0; rt < 2; ++rt) {
            ah[rt] = *(const bf16x8*)&Ah[rt * 16 + c16][ko + q * 8];
            al[rt] = *(const bf16x8*)&Al[rt * 16 + c16][ko + q * 8];
        }
#pragma unroll
        for (int rt = 0; rt < 2; ++rt)
#pragma unroll
            for (int g = 0; g < 4; ++g) {
                acc[rt][g] = __builtin_amdgcn_mfma_f32_16x16x32_bf16(ah[rt], bh[g], acc[rt][g], 0, 0, 0);
                acc[rt][g] = __builtin_amdgcn_mfma_f32_16x16x32_bf16(al[rt], bh[g], acc[rt][g], 0, 0, 0);
                acc[rt][g] = __builtin_amdgcn_mfma_f32_16x16x32_bf16(ah[rt], bl[g], acc[rt][g], 0, 0, 0);
            }
    }

    // ---- phase 3: LSTM elementwise (unit u = 16*w + c16 lane-local)
    const int u = 16 * w + c16;
    const float bi = bc[u], bfv = bc[64 + u], bo = bc[128 + u], bg = bc[192 + u];
    float h2v[2][4];
#pragma unroll
    for (int rt = 0; rt < 2; ++rt) {
        const int n = n0 + rt;
#pragma unroll
        for (int reg = 0; reg < 4; ++reg) {
            const int bb = q * 4 + reg;
            const size_t idx = ((size_t)n * 16 + bb) * HH + u;
            const float ig = sigmoidf_(acc[rt][0][reg] + bi);
            const float fg = sigmoidf_(acc[rt][1][reg] + bfv);
            const float og = sigmoidf_(acc[rt][2][reg] + bo);
            const float gg = tanhf_(acc[rt][3][reg] + bg);
            const float c2 = fg * c[idx] + ig * gg;
            const float h2 = og * tanhf_(c2);
            c[idx] = c2;
            h[idx] = h2;
            h2v[rt][reg] = h2;
        }
    }

    if (jslot >= 0) {
        const float w0u = W0[u * 2], w1u = W0[u * 2 + 1];
#pragma unroll
        for (int rt = 0; rt < 2; ++rt) {
#pragma unroll
            for (int reg = 0; reg < 4; ++reg) {
                float s0 = h2v[rt][reg] * w0u;
                float s1 = h2v[rt][reg] * w1u;
#pragma unroll
                for (int d = 1; d <= 8; d <<= 1) {
                    s0 += __shfl_xor(s0, d, 64);
                    s1 += __shfl_xor(s1, d, 64);
                }
                if (c16 == 0) {
                    const int lr = rt * 16 + q * 4 + reg;
                    proj[w][lr][0] = s0;
                    proj[w][lr][1] = s1;
                }
            }
        }
        __syncthreads();
        if (tid < 64) {
            const int lr = tid >> 1, comp = tid & 1;
            const float v = proj[0][lr][comp] + proj[1][lr][comp] +
                            proj[2][lr][comp] + proj[3][lr][comp] + b0[comp];
            const float y = tanhf_(v);
            const int n = n0 + (lr >> 4);
            const int bb = lr & 15;
            xout[((size_t)n * 16 + bb) * 2 + comp] = y;
            out[(((size_t)bb * FUT + jslot) * NN + n) * 2 + comp] = y;
        }
    }
}

// ---------------------------------------------------------------------------
extern "C" void kernel_launch(void* const* d_in, const int* in_sizes, int n_in,
                              void* d_out, int out_size, void* d_ws, size_t ws_size,
                              hipStream_t stream)
{
    const float* input = (const float*)d_in[0];   // [B,T,N,2]
    const float* L     = (const float*)d_in[1];   // [N,N]
    const float* W     = (const float*)d_in[2];   // [198,256]
    const float* bc    = (const float*)d_in[3];   // [256]
    const float* W0    = (const float*)d_in[4];   // [64,2]
    const float* b0    = (const float*)d_in[5];   // [2]

    char* ws = (char*)d_ws;
    size_t off = 0;
    auto carve = [&](size_t bytes) {
        void* p = ws + off;
        off += (bytes + 255) & ~(size_t)255;
        return p;
    };
    int*   cols  = (int*)  carve((size_t)NN * ELLW * 4);
    float* vals  = (float*)carve((size_t)NN * ELLW * 4);
    int*   cnt   = (int*)  carve((size_t)NN * 4);
    float* t1h   = (float*)carve((size_t)NN * 16 * HH * 4);
    float* t1x   = (float*)carve((size_t)NN * 16 * 2 * 4);
    float* h     = (float*)carve((size_t)NN * 16 * HH * 4);
    float* c     = (float*)carve((size_t)NN * 16 * HH * 4);
    float* xbuf  = (float*)carve((size_t)NN * 16 * 2 * 4);
    float* xtall = (float*)carve((size_t)TT * NN * 16 * 2 * 4);
    short* Wh    = (short*)carve((size_t)GG * KP * 2);
    short* Wl    = (short*)carve((size_t)GG * KP * 2);
    float* out   = (float*)d_out;

    build_ell<<<NN, 256, 0, stream>>>(L, cols, vals, cnt);
    wt_prep<<<GG, 256, 0, stream>>>(W, Wh, Wl);
    x_trans<<<(TT * NN * 16 * 2) / 256, 256, 0, stream>>>(input, xtall);
    hipMemsetAsync(h, 0, (size_t)NN * 16 * HH * 4, stream);
    hipMemsetAsync(c, 0, (size_t)NN * 16 * HH * 4, stream);

    for (int t = 0; t < TT; ++t) {
        const float* xt = xtall + (size_t)t * NN * 16 * 2;
        spmm_t1<<<NN, 256, 0, stream>>>(xt, h, cols, vals, cnt, t1h, t1x);
        cell_fused<<<NN / 2, 256, 0, stream>>>(xt, h, c, t1h, t1x, cols, vals, cnt,
                                               Wh, Wl, bc, W0, b0, xbuf, out,
                                               (t == TT - 1) ? 0 : -1);
    }
    for (int jstep = 1; jstep < FUT; ++jstep) {
        spmm_t1<<<NN, 256, 0, stream>>>(xbuf, h, cols, vals, cnt, t1h, t1x);
        cell_fused<<<NN / 2, 256, 0, stream>>>(xbuf, h, c, t1h, t1x, cols, vals, cnt,
                                               Wh, Wl, bc, W0, b0, xbuf, out, jstep);
    }
}

// Round 15
// 1180.355 us; speedup vs baseline: 1.1800x; 1.0138x over previous
//
#include <hip/hip_runtime.h>
#include <cstdint>
#include <cstddef>

#define NN   2048
#define BB   16
#define TT   12
#define FUT  12
#define HH   64
#define GG   256     // 4*H
#define KP   224     // K=198 padded to 7*32
#define ELLW 72
#define ASTR 232     // LDS A row stride in shorts (464 B, 16B-aligned)

typedef __attribute__((ext_vector_type(8))) short bf16x8;
typedef __attribute__((ext_vector_type(4))) float f32x4;

__device__ __forceinline__ float sigmoidf_(float x) {
    return 1.f / (1.f + __expf(-x));
}
__device__ __forceinline__ float tanhf_(float x) {
    const float e = __expf(2.f * x);
    return 1.f - 2.f / (e + 1.f);
}
__device__ __forceinline__ unsigned short f2bf(float x) {
    unsigned u = __builtin_bit_cast(unsigned, x);
    u += 0x7fffu + ((u >> 16) & 1u);
    return (unsigned short)(u >> 16);
}
__device__ __forceinline__ float bf2f(unsigned short s) {
    unsigned u = ((unsigned)s) << 16;
    return __builtin_bit_cast(float, u);
}

// ---------------------------------------------------------------------------
// ELL of L, deterministic ascending-column order, padded to multiple of 4
// (pad entries: col=n, val=0 -> exact no-op).
// ---------------------------------------------------------------------------
__global__ __launch_bounds__(256) void build_ell(
    const float* __restrict__ L, int* __restrict__ cols,
    float* __restrict__ vals, int* __restrict__ cnt)
{
    const int n = blockIdx.x;
    const int t = threadIdx.x;
    const float* row = L + (size_t)n * NN;
    float v[8];
    int c = 0;
#pragma unroll
    for (int i = 0; i < 8; ++i) {
        v[i] = row[t * 8 + i];
        c += (v[i] != 0.f);
    }
    __shared__ int s[256];
    s[t] = c;
    __syncthreads();
    for (int d = 1; d < 256; d <<= 1) {
        int add = (t >= d) ? s[t - d] : 0;
        __syncthreads();
        s[t] += add;
        __syncthreads();
    }
    int o = s[t] - c;
#pragma unroll
    for (int i = 0; i < 8; ++i) {
        if (v[i] != 0.f) {
            if (o < ELLW) {
                cols[n * ELLW + o] = t * 8 + i;
                vals[n * ELLW + o] = v[i];
            }
            ++o;
        }
    }
    if (t == 255) {
        int cn = (s[255] < ELLW) ? s[255] : ELLW;
        int cn4 = (cn + 3) & ~3;
        if (cn4 > ELLW) cn4 = ELLW;
        for (int p = cn; p < cn4; ++p) {
            cols[n * ELLW + p] = n;
            vals[n * ELLW + p] = 0.f;
        }
        cnt[n] = cn4;
    }
}

// ---------------------------------------------------------------------------
// W [198][256] fp32 -> W_t hi/lo [256][224] bf16 (transposed, K-padded).
// ---------------------------------------------------------------------------
__global__ __launch_bounds__(256) void wt_prep(
    const float* __restrict__ W, short* __restrict__ Wh, short* __restrict__ Wl)
{
    const int col = blockIdx.x;
    const int k = threadIdx.x;
    if (k < KP) {
        const float x = (k < 198) ? W[(size_t)k * GG + col] : 0.f;
        const unsigned short h = f2bf(x);
        const unsigned short l = f2bf(x - bf2f(h));
        Wh[(size_t)col * KP + k] = (short)h;
        Wl[(size_t)col * KP + k] = (short)l;
    }
}

// ---------------------------------------------------------------------------
// input [B][T][N][2] -> xt_all [T][N][B][2]  (node-major x, batch inner)
// ---------------------------------------------------------------------------
__global__ __launch_bounds__(256) void x_trans(
    const float* __restrict__ input, float* __restrict__ xt)
{
    const int o = blockIdx.x * 256 + threadIdx.x;   // 786432 total
    const int e = o & 1;
    const int b = (o >> 1) & 15;
    const int n = (o >> 5) & (NN - 1);
    const int t = o >> 16;
    xt[o] = input[(((size_t)b * TT + t) * NN + n) * 2 + e];
}

// ---------------------------------------------------------------------------
// t1h[n][b][0..63] (h-part, 256B rows) and t1x[n][b][0..1] (x-part, dense).
// One block per node, 4 waves = 4 h-quad-slices, lane = (b=lane>>2, j=lane&3).
// ---------------------------------------------------------------------------
__global__ __launch_bounds__(256) void spmm_t1(
    const float* __restrict__ xt,      // [N][16][2]
    const float* __restrict__ h,       // [N][16][64]
    const int* __restrict__ cols, const float* __restrict__ vals,
    const int* __restrict__ cnt,
    float* __restrict__ t1h, float* __restrict__ t1x)
{
    const int w = threadIdx.x >> 6, lane = threadIdx.x & 63;
    const int b = lane >> 2, j = lane & 3;
    const int n = blockIdx.x;
    const int cn = cnt[n];
    const int* cp = cols + n * ELLW;
    const float* vp = vals + n * ELLW;
    const int qoff = (4 * w + j) * 4;
    float a0 = 0.f, a1 = 0.f, a2 = 0.f, a3 = 0.f;
    float ax0 = 0.f, ax1 = 0.f;
#pragma unroll 2
    for (int jj = 0; jj < cn; jj += 4) {
#pragma unroll
        for (int u = 0; u < 4; ++u) {
            const int m = cp[jj + u];
            const float v = vp[jj + u];
            const size_t mb = (size_t)m * 16 + b;
            const float4 g = *(const float4*)&h[mb * HH + qoff];
            a0 += v * g.x; a1 += v * g.y; a2 += v * g.z; a3 += v * g.w;
            if (w == 0) {
                const float2 xg = *(const float2*)&xt[mb * 2];
                ax0 += v * xg.x; ax1 += v * xg.y;
            }
        }
    }
    *(float4*)&t1h[((size_t)n * 16 + b) * HH + qoff] = (float4){a0, a1, a2, a3};
    if (w == 0 && j == 0) {
        t1x[((size_t)n * 16 + b) * 2]     = ax0;
        t1x[((size_t)n * 16 + b) * 2 + 1] = ax1;
    }
}

// ---------------------------------------------------------------------------
// Fused cell step, node-major: block = 2 nodes x 16 batches = 32 A-rows,
// grid 1024 -> 4 blocks/CU (30.7 KB LDS, VGPR budget relaxed to 4 waves/SIMD).
//   phase 1: waves = f-slices; stage comb/t1, gather t2 (256B coalesced rows),
//            split to bf16 hi/lo LDS tiles.
//   phase 2: MFMA GEMM; wave w owns gate-strided col-tiles {w,w+4,w+8,w+12}.
//   phase 3: LSTM elementwise; projection via LDS reduce.
// A k-cols: [0..65]=comb(x0,x1,h0..63)  [66..131]=t1  [132..197]=t2  [198..]=0
// ---------------------------------------------------------------------------
__global__ __launch_bounds__(256, 4) void cell_fused(
    const float* __restrict__ xt,      // [N][16][2]
    float* __restrict__ h, float* __restrict__ c,   // [N][16][64]
    const float* __restrict__ t1h,     // [N][16][64]
    const float* __restrict__ t1x,     // [N][16][2]
    const int* __restrict__ cols, const float* __restrict__ vals,
    const int* __restrict__ cnt,
    const short* __restrict__ Wh, const short* __restrict__ Wl,
    const float* __restrict__ bc,
    const float* __restrict__ W0, const float* __restrict__ b0,
    float* __restrict__ xout,          // [N][16][2]
    float* __restrict__ out, int jslot)
{
    __shared__ unsigned short Ah[32][ASTR];
    __shared__ unsigned short Al[32][ASTR];
    __shared__ float proj[4][32][2];
    const int tid = threadIdx.x, w = tid >> 6, lane = tid & 63;
    const int q = lane >> 4, c16 = lane & 15;
    const int b = lane >> 2, j = lane & 3;
    const int n0 = blockIdx.x * 2;
    const int qoff = (4 * w + j) * 4;            // f-slice float offset (0..60)

    auto put = [&](int r, int k, float v) {
        const unsigned short hi = f2bf(v);
        Ah[r][k] = hi;
        Al[r][k] = f2bf(v - bf2f(hi));
    };

    // ---- zero pad cols 198..231
    {
        const int zr = tid >> 3, zs = tid & 7;
#pragma unroll
        for (int k0 = 198; k0 < 232; k0 += 8) {
            const int k = k0 + zs;
            if (k < 232) { Ah[zr][k] = 0; Al[zr][k] = 0; }
        }
    }

    // ---- phase 1: per node, stage + gather
#pragma unroll
    for (int ln = 0; ln < 2; ++ln) {
        const int n = n0 + ln;
        const size_t rb = (size_t)n * 16 + b;
        const int r = ln * 16 + b;
        const float4 hq = *(const float4*)&h[rb * HH + qoff];
        const float4 tq = *(const float4*)&t1h[rb * HH + qoff];
        float xo0 = 0.f, xo1 = 0.f, t160 = 0.f, t161 = 0.f;
        if (w == 1) {
            const float2 xv = *(const float2*)&xt[rb * 2];
            xo0 = xv.x; xo1 = xv.y;
            const float2 tv = *(const float2*)&t1x[rb * 2];
            t160 = tv.x; t161 = tv.y;
        }
        const int cn = cnt[n];
        const int* cp = cols + n * ELLW;
        const float* vp = vals + n * ELLW;
        float a0 = 0.f, a1 = 0.f, a2 = 0.f, a3 = 0.f, ax0 = 0.f, ax1 = 0.f;
#pragma unroll 4
        for (int jj = 0; jj < cn; ++jj) {
            const int m = cp[jj];
            const float v = vp[jj];
            const size_t mb = (size_t)m * 16 + b;
            const float4 g = *(const float4*)&t1h[mb * HH + qoff];
            a0 += v * g.x; a1 += v * g.y; a2 += v * g.z; a3 += v * g.w;
            if (w == 1) {
                const float2 gx = *(const float2*)&t1x[mb * 2];
                ax0 += v * gx.x; ax1 += v * gx.y;
            }
        }
        put(r, 2 + qoff + 0, hq.x);  put(r, 2 + qoff + 1, hq.y);
        put(r, 2 + qoff + 2, hq.z);  put(r, 2 + qoff + 3, hq.w);
        put(r, 68 + qoff + 0, tq.x); put(r, 68 + qoff + 1, tq.y);
        put(r, 68 + qoff + 2, tq.z); put(r, 68 + qoff + 3, tq.w);
        put(r, 134 + qoff + 0, 2.f * a0 - hq.x);
        put(r, 134 + qoff + 1, 2.f * a1 - hq.y);
        put(r, 134 + qoff + 2, 2.f * a2 - hq.z);
        put(r, 134 + qoff + 3, 2.f * a3 - hq.w);
        if (w == 1 && j == 0) {
            put(r, 0, xo0);   put(r, 1, xo1);
            put(r, 66, t160); put(r, 67, t161);
            put(r, 132, 2.f * ax0 - xo0);
            put(r, 133, 2.f * ax1 - xo1);
        }
    }
    __syncthreads();

    // ---- phase 2: MFMA GEMM (2 row-tiles x 4 gate-tiles)
    f32x4 acc[2][4];
#pragma unroll
    for (int rt = 0; rt < 2; ++rt)
#pragma unroll
        for (int g = 0; g < 4; ++g) acc[rt][g] = (f32x4){0.f, 0.f, 0.f, 0.f};

    for (int kc = 0; kc < 7; ++kc) {
        const int ko = kc * 32 + q * 8;
        bf16x8 ah[2], al[2];
#pragma unroll
        for (int rt = 0; rt < 2; ++rt) {
            ah[rt] = *(const bf16x8*)&Ah[rt * 16 + c16][ko];
            al[rt] = *(const bf16x8*)&Al[rt * 16 + c16][ko];
        }
        bf16x8 bh[4], bl[4];
#pragma unroll
        for (int g = 0; g < 4; ++g) {
            const int col = (w + 4 * g) * 16 + c16;
            const size_t wo = (size_t)col * KP + ko;
            bh[g] = *(const bf16x8*)(Wh + wo);
            bl[g] = *(const bf16x8*)(Wl + wo);
        }
#pragma unroll
        for (int rt = 0; rt < 2; ++rt)
#pragma unroll
            for (int g = 0; g < 4; ++g) {
                acc[rt][g] = __builtin_amdgcn_mfma_f32_16x16x32_bf16(ah[rt], bh[g], acc[rt][g], 0, 0, 0);
                acc[rt][g] = __builtin_amdgcn_mfma_f32_16x16x32_bf16(al[rt], bh[g], acc[rt][g], 0, 0, 0);
                acc[rt][g] = __builtin_amdgcn_mfma_f32_16x16x32_bf16(ah[rt], bl[g], acc[rt][g], 0, 0, 0);
            }
    }

    // ---- phase 3: LSTM elementwise (unit u = 16*w + c16 lane-local)
    const int u = 16 * w + c16;
    const float bi = bc[u], bfv = bc[64 + u], bo = bc[128 + u], bg = bc[192 + u];
    float h2v[2][4];
#pragma unroll
    for (int rt = 0; rt < 2; ++rt) {
        const int n = n0 + rt;
#pragma unroll
        for (int reg = 0; reg < 4; ++reg) {
            const int bb = q * 4 + reg;
            const size_t idx = ((size_t)n * 16 + bb) * HH + u;
            const float ig = sigmoidf_(acc[rt][0][reg] + bi);
            const float fg = sigmoidf_(acc[rt][1][reg] + bfv);
            const float og = sigmoidf_(acc[rt][2][reg] + bo);
            const float gg = tanhf_(acc[rt][3][reg] + bg);
            const float c2 = fg * c[idx] + ig * gg;
            const float h2 = og * tanhf_(c2);
            c[idx] = c2;
            h[idx] = h2;
            h2v[rt][reg] = h2;
        }
    }

    if (jslot >= 0) {
        const float w0u = W0[u * 2], w1u = W0[u * 2 + 1];
#pragma unroll
        for (int rt = 0; rt < 2; ++rt) {
#pragma unroll
            for (int reg = 0; reg < 4; ++reg) {
                float s0 = h2v[rt][reg] * w0u;
                float s1 = h2v[rt][reg] * w1u;
#pragma unroll
                for (int d = 1; d <= 8; d <<= 1) {
                    s0 += __shfl_xor(s0, d, 64);
                    s1 += __shfl_xor(s1, d, 64);
                }
                if (c16 == 0) {
                    const int lr = rt * 16 + q * 4 + reg;
                    proj[w][lr][0] = s0;
                    proj[w][lr][1] = s1;
                }
            }
        }
        __syncthreads();
        if (tid < 64) {
            const int lr = tid >> 1, comp = tid & 1;
            const float v = proj[0][lr][comp] + proj[1][lr][comp] +
                            proj[2][lr][comp] + proj[3][lr][comp] + b0[comp];
            const float y = tanhf_(v);
            const int n = n0 + (lr >> 4);
            const int bb = lr & 15;
            xout[((size_t)n * 16 + bb) * 2 + comp] = y;
            out[(((size_t)bb * FUT + jslot) * NN + n) * 2 + comp] = y;
        }
    }
}

// ---------------------------------------------------------------------------
extern "C" void kernel_launch(void* const* d_in, const int* in_sizes, int n_in,
                              void* d_out, int out_size, void* d_ws, size_t ws_size,
                              hipStream_t stream)
{
    const float* input = (const float*)d_in[0];   // [B,T,N,2]
    const float* L     = (const float*)d_in[1];   // [N,N]
    const float* W     = (const float*)d_in[2];   // [198,256]
    const float* bc    = (const float*)d_in[3];   // [256]
    const float* W0    = (const float*)d_in[4];   // [64,2]
    const float* b0    = (const float*)d_in[5];   // [2]

    char* ws = (char*)d_ws;
    size_t off = 0;
    auto carve = [&](size_t bytes) {
        void* p = ws + off;
        off += (bytes + 255) & ~(size_t)255;
        return p;
    };
    int*   cols  = (int*)  carve((size_t)NN * ELLW * 4);
    float* vals  = (float*)carve((size_t)NN * ELLW * 4);
    int*   cnt   = (int*)  carve((size_t)NN * 4);
    float* t1h   = (float*)carve((size_t)NN * 16 * HH * 4);
    float* t1x   = (float*)carve((size_t)NN * 16 * 2 * 4);
    float* h     = (float*)carve((size_t)NN * 16 * HH * 4);
    float* c     = (float*)carve((size_t)NN * 16 * HH * 4);
    float* xbuf  = (float*)carve((size_t)NN * 16 * 2 * 4);
    float* xtall = (float*)carve((size_t)TT * NN * 16 * 2 * 4);
    short* Wh    = (short*)carve((size_t)GG * KP * 2);
    short* Wl    = (short*)carve((size_t)GG * KP * 2);
    float* out   = (float*)d_out;

    build_ell<<<NN, 256, 0, stream>>>(L, cols, vals, cnt);
    wt_prep<<<GG, 256, 0, stream>>>(W, Wh, Wl);
    x_trans<<<(TT * NN * 16 * 2) / 256, 256, 0, stream>>>(input, xtall);
    hipMemsetAsync(h, 0, (size_t)NN * 16 * HH * 4, stream);
    hipMemsetAsync(c, 0, (size_t)NN * 16 * HH * 4, stream);

    for (int t = 0; t < TT; ++t) {
        const float* xt = xtall + (size_t)t * NN * 16 * 2;
        spmm_t1<<<NN, 256, 0, stream>>>(xt, h, cols, vals, cnt, t1h, t1x);
        cell_fused<<<NN / 2, 256, 0, stream>>>(xt, h, c, t1h, t1x, cols, vals, cnt,
                                               Wh, Wl, bc, W0, b0, xbuf, out,
                                               (t == TT - 1) ? 0 : -1);
    }
    for (int jstep = 1; jstep < FUT; ++jstep) {
        spmm_t1<<<NN, 256, 0, stream>>>(xbuf, h, cols, vals, cnt, t1h, t1x);
        cell_fused<<<NN / 2, 256, 0, stream>>>(xbuf, h, c, t1h, t1x, cols, vals, cnt,
                                               Wh, Wl, bc, W0, b0, xbuf, out, jstep);
    }
}